// Round 5
// baseline (5091.153 us; speedup 1.0000x reference)
//
#include <hip/hip_runtime.h>
#include <hip/hip_bf16.h>
#include <math.h>

typedef __hip_bfloat16 bf16;
typedef __attribute__((ext_vector_type(8))) short bf16x8;   // 8 bf16 = 4 VGPR
typedef __attribute__((ext_vector_type(4))) float f32x4;

#define NW   16384
#define LC   20
#define EDIM 64
#define HC   256
#define HW   512
#define SEQ  128
#define NOUT 50
#define NWB  64      // word-kernel block count (must all be co-resident)

__device__ __forceinline__ float sigf(float x) { return 1.0f / (1.0f + expf(-x)); }
__device__ __forceinline__ float bu2f(unsigned short b) {
  union { float f; unsigned u; } z; z.u = ((unsigned)b) << 16; return z.f;
}
__device__ __forceinline__ unsigned short f2bu(float f) {
  bf16 h = __float2bfloat16(f);
  return *reinterpret_cast<unsigned short*>(&h);
}
__device__ __forceinline__ bf16x8 ld8(const unsigned short* p) {
  return *reinterpret_cast<const bf16x8*>(p);
}
#define MFMA(a, b, c) __builtin_amdgcn_mfma_f32_16x16x32_bf16(a, b, c, 0, 0, 0)

// ---------------------------------------------------------------------------
// Persistent char LSTM: one launch, 512 blocks x 32 words. h in LDS
// (double-buffered), c in registers. Weights (gate-interleaved bf16) stream
// from L2. One __syncthreads per step. last written once per word.
// Wave w covers gate-cols [w*256, w*256+256) in 4 chunks of 64.
// ---------------------------------------------------------------------------
__global__ __launch_bounds__(256) void char_lstm(
    const int* __restrict__ x, const unsigned short* __restrict__ embb,
    const unsigned short* __restrict__ Wc, const float* __restrict__ bc,
    unsigned short* __restrict__ last, const int* __restrict__ len) {
  __shared__ unsigned short Hs[2][32][264];   // 33.8 KB
  __shared__ float gt[4][32][68];             // 34.8 KB
  const int tid = threadIdx.x;
  const int w = tid >> 6, l = tid & 63;
  const int l16 = l & 15, lk8 = (l >> 4) * 8;
  const int hi = l >> 5;              // 0/1
  const int wl = l & 31;              // owned word (update phase)
  const int w0 = blockIdx.x * 32;
  const int mylen = len[w0 + wl];
  float cst[4][8];
#pragma unroll
  for (int c = 0; c < 4; ++c)
#pragma unroll
    for (int i = 0; i < 8; ++i) cst[c][i] = 0.f;

  for (int t = 0; t < LC; ++t) {
    const int cur = t & 1, nxt = cur ^ 1;
    const int xi0 = x[(w0 + l16) * LC + t];
    const int xi1 = x[(w0 + 16 + l16) * LC + t];
#pragma unroll
    for (int c = 0; c < 4; ++c) {
      const int cc0 = w * 256 + c * 64;
      f32x4 acc[2][4] = {};
#pragma unroll
      for (int kk = 0; kk < 2; ++kk) {          // K 0..63: embedding
        const int k = kk * 32 + lk8;
        bf16x8 a0 = ld8(embb + (size_t)xi0 * EDIM + k);
        bf16x8 a1 = ld8(embb + (size_t)xi1 * EDIM + k);
        const unsigned short* wp = Wc + (size_t)(cc0 + l16) * 320 + k;
#pragma unroll
        for (int n = 0; n < 4; ++n) {
          bf16x8 bv = ld8(wp + n * 16 * 320);
          acc[0][n] = MFMA(a0, bv, acc[0][n]);
          acc[1][n] = MFMA(a1, bv, acc[1][n]);
        }
      }
      if (t > 0) {
#pragma unroll
        for (int kk = 2; kk < 10; ++kk) {       // K 64..319: h(t-1) from LDS
          const int k = kk * 32 + lk8;
          bf16x8 a0 = ld8(&Hs[cur][l16][k - 64]);
          bf16x8 a1 = ld8(&Hs[cur][16 + l16][k - 64]);
          const unsigned short* wp = Wc + (size_t)(cc0 + l16) * 320 + k;
#pragma unroll
          for (int n = 0; n < 4; ++n) {
            bf16x8 bv = ld8(wp + n * 16 * 320);
            acc[0][n] = MFMA(a0, bv, acc[0][n]);
            acc[1][n] = MFMA(a1, bv, acc[1][n]);
          }
        }
      }
      const int cr = (l >> 4) * 4;
#pragma unroll
      for (int m = 0; m < 2; ++m)
#pragma unroll
        for (int n = 0; n < 4; ++n)
#pragma unroll
          for (int e = 0; e < 4; ++e)
            gt[w][m * 16 + cr + e][n * 16 + l16] = acc[m][n][e];
      // same-wave LDS RAW: compiler inserts lgkmcnt waits
#pragma unroll
      for (int i = 0; i < 8; ++i) {
        const int ul = 2 * i + hi;              // unit-local 0..15
        const int col = 4 * ul;
        float gi = gt[w][wl][col + 0] + bc[cc0 + col + 0];
        float gf = gt[w][wl][col + 1] + bc[cc0 + col + 1];
        float gg = gt[w][wl][col + 2] + bc[cc0 + col + 2];
        float go = gt[w][wl][col + 3] + bc[cc0 + col + 3];
        float cc = sigf(gf) * cst[c][i] + sigf(gi) * tanhf(gg);
        cst[c][i] = cc;
        float h = sigf(go) * tanhf(cc);
        const int unit = (cc0 >> 2) + ul;
        Hs[nxt][wl][unit] = f2bu(h);
        if (t == mylen - 1)
          last[(size_t)(w0 + wl) * HC + unit] = f2bu(h);
        else if (mylen == 0 && t == 0)
          last[(size_t)(w0 + wl) * HC + unit] = 0;   // bf16 +0
      }
    }
    __syncthreads();   // Hs[nxt] complete before next step's reads
  }
}

// ---------------------------------------------------------------------------
// Device-scope barrier for the persistent word kernel. One-shot counters,
// zeroed each launch. Release: threadfence before arrive. Acquire: fence
// (L1 invalidate) after observing full count, by all threads.
// ---------------------------------------------------------------------------
__device__ __forceinline__ void gbar(int* cnt) {
  __syncthreads();
  if (threadIdx.x == 0) {
    __threadfence();
    atomicAdd(cnt, 1);
    while (__hip_atomic_load(cnt, __ATOMIC_RELAXED, __HIP_MEMORY_SCOPE_AGENT) < NWB)
      __builtin_amdgcn_s_sleep(2);
  }
  __syncthreads();
  __threadfence();   // acquire: invalidate L1 so h reads see other XCDs' writes
}

// ---------------------------------------------------------------------------
// Persistent word BiLSTM: one launch, 64 blocks (dir = bx>>5, 64 gate-cols
// each). M=128 batches per block. h double-buffered in global (L2-hot),
// c in registers. Spin barrier per step.
// ---------------------------------------------------------------------------
__global__ __launch_bounds__(256) void word_lstm(
    const unsigned short* __restrict__ last,
    const unsigned short* __restrict__ Wf, const unsigned short* __restrict__ Wb,
    const float* __restrict__ bfi, const float* __restrict__ bbi,
    unsigned short* __restrict__ hb,    // [2 buf][2 dir][128][512]
    unsigned short* __restrict__ hs,    // [16384][1024]
    int* __restrict__ cnts) {
  __shared__ float gt[128][69];         // 35.3 KB
  const int tid = threadIdx.x;
  const int w = tid >> 6, l = tid & 63;
  const int l16 = l & 15, lk8 = (l >> 4) * 8;
  const int dir = blockIdx.x >> 5;
  const int nb = blockIdx.x & 31;
  const int c0 = nb * 64;               // gate-col base (of 2048)
  const int u0 = nb * 16;               // unit base (of 512)
  const unsigned short* W = dir ? Wb : Wf;
  const float* bias = dir ? bbi : bfi;
  const int ub = tid & 127;             // owned batch
  const int uhi = tid >> 7;
  float cst[8];
#pragma unroll
  for (int i = 0; i < 8; ++i) cst[i] = 0.f;

  for (int t = 0; t < SEQ; ++t) {
    const int cur = t & 1;
    const int pos = dir ? (SEQ - 1 - t) : t;
    const unsigned short* hprev = hb + (size_t)(((cur ^ 1) << 1) + dir) * SEQ * HW;
    const int bt0 = w * 32 + l16, bt1 = bt0 + 16;
    f32x4 acc[2][4] = {};
#pragma unroll
    for (int kk = 0; kk < 8; ++kk) {            // K 0..255: word_seq (last)
      const int k = kk * 32 + lk8;
      bf16x8 a0 = ld8(last + ((size_t)bt0 * SEQ + pos) * HC + k);
      bf16x8 a1 = ld8(last + ((size_t)bt1 * SEQ + pos) * HC + k);
      const unsigned short* wp = W + (size_t)(c0 + l16) * 768 + k;
#pragma unroll
      for (int n = 0; n < 4; ++n) {
        bf16x8 bv = ld8(wp + n * 16 * 768);
        acc[0][n] = MFMA(a0, bv, acc[0][n]);
        acc[1][n] = MFMA(a1, bv, acc[1][n]);
      }
    }
    if (t > 0) {
#pragma unroll
      for (int kk = 8; kk < 24; ++kk) {         // K 256..767: h(t-1)
        const int k = kk * 32 + lk8;
        bf16x8 a0 = ld8(hprev + (size_t)bt0 * HW + (k - HC));
        bf16x8 a1 = ld8(hprev + (size_t)bt1 * HW + (k - HC));
        const unsigned short* wp = W + (size_t)(c0 + l16) * 768 + k;
#pragma unroll
        for (int n = 0; n < 4; ++n) {
          bf16x8 bv = ld8(wp + n * 16 * 768);
          acc[0][n] = MFMA(a0, bv, acc[0][n]);
          acc[1][n] = MFMA(a1, bv, acc[1][n]);
        }
      }
    }
    const int cr = (l >> 4) * 4;
#pragma unroll
    for (int m = 0; m < 2; ++m)
#pragma unroll
      for (int n = 0; n < 4; ++n)
#pragma unroll
        for (int e = 0; e < 4; ++e)
          gt[w * 32 + m * 16 + cr + e][n * 16 + l16] = acc[m][n][e];
    __syncthreads();
    unsigned short* hcur = hb + (size_t)((cur << 1) + dir) * SEQ * HW;
#pragma unroll
    for (int i = 0; i < 8; ++i) {
      const int ul = 2 * i + uhi;               // unit-local 0..15
      const int col = 4 * ul;
      float gi = gt[ub][col + 0] + bias[c0 + col + 0];
      float gf = gt[ub][col + 1] + bias[c0 + col + 1];
      float gg = gt[ub][col + 2] + bias[c0 + col + 2];
      float go = gt[ub][col + 3] + bias[c0 + col + 3];
      float cc = sigf(gf) * cst[i] + sigf(gi) * tanhf(gg);
      cst[i] = cc;
      const unsigned short h16 = f2bu(sigf(go) * tanhf(cc));
      hcur[(size_t)ub * HW + u0 + ul] = h16;
      hs[((size_t)ub * SEQ + pos) * 1024 + dir * HW + u0 + ul] = h16;
    }
    if (t < SEQ - 1) gbar(cnts + t);
  }
}

// ---------------------------------------------------------------------------
// MLP GEMM: out = relu(A @ W^T + bias), bf16 in/out, 128x64 per block.
// ---------------------------------------------------------------------------
__global__ __launch_bounds__(256) void mlp_gemm(
    const unsigned short* __restrict__ A, int lda,
    const unsigned short* __restrict__ W, int ldw,
    const float* __restrict__ bias, unsigned short* __restrict__ out,
    int ldo, int nk, int relu) {
  const int tid = threadIdx.x;
  const int w = tid >> 6, l = tid & 63;
  const int l16 = l & 15, lk8 = (l >> 4) * 8;
  const int row0 = blockIdx.y * 128 + w * 32;
  const int col0 = blockIdx.x * 64;
  f32x4 acc[2][4] = {};
  for (int kk = 0; kk < nk; ++kk) {
    const int k = kk * 32 + lk8;
    bf16x8 a0 = ld8(A + (size_t)(row0 + l16) * lda + k);
    bf16x8 a1 = ld8(A + (size_t)(row0 + 16 + l16) * lda + k);
    const unsigned short* wp = W + (size_t)(col0 + l16) * ldw + k;
    bf16x8 bb[4];
#pragma unroll
    for (int n = 0; n < 4; ++n) bb[n] = ld8(wp + n * 16 * ldw);
#pragma unroll
    for (int n = 0; n < 4; ++n) {
      acc[0][n] = MFMA(a0, bb[n], acc[0][n]);
      acc[1][n] = MFMA(a1, bb[n], acc[1][n]);
    }
  }
  const int cr = (l >> 4) * 4;
#pragma unroll
  for (int m = 0; m < 2; ++m)
#pragma unroll
    for (int n = 0; n < 4; ++n)
#pragma unroll
      for (int e = 0; e < 4; ++e) {
        const int r = row0 + m * 16 + cr + e;
        const int c = col0 + n * 16 + l16;
        float v = acc[m][n][e] + bias[c];
        if (relu) v = fmaxf(v, 0.f);
        out[(size_t)r * ldo + c] = f2bu(v);
      }
}

// ---------------------------------------------------------------------------
// Logits (MFMA, N=64 padded) + log_softmax over 50, fused. 128 rows/block.
// ---------------------------------------------------------------------------
__global__ __launch_bounds__(256) void logits_fused(
    const unsigned short* __restrict__ h2, const unsigned short* __restrict__ W3p,
    const float* __restrict__ b3, float* __restrict__ out) {
  __shared__ float gt[128][68];
  __shared__ float lseb[128];
  const int tid = threadIdx.x;
  const int w = tid >> 6, l = tid & 63;
  const int l16 = l & 15, lk8 = (l >> 4) * 8;
  const int r0 = blockIdx.x * 128;
  const int rr0 = w * 32 + l16, rr1 = rr0 + 16;
  f32x4 acc[2][4] = {};
#pragma unroll
  for (int kk = 0; kk < 8; ++kk) {
    const int k = kk * 32 + lk8;
    bf16x8 a0 = ld8(h2 + (size_t)(r0 + rr0) * 256 + k);
    bf16x8 a1 = ld8(h2 + (size_t)(r0 + rr1) * 256 + k);
#pragma unroll
    for (int n = 0; n < 4; ++n) {
      bf16x8 bv = ld8(W3p + (size_t)(n * 16 + l16) * 256 + k);
      acc[0][n] = MFMA(a0, bv, acc[0][n]);
      acc[1][n] = MFMA(a1, bv, acc[1][n]);
    }
  }
  const int cr = (l >> 4) * 4;
#pragma unroll
  for (int m = 0; m < 2; ++m)
#pragma unroll
    for (int n = 0; n < 4; ++n)
#pragma unroll
      for (int e = 0; e < 4; ++e) {
        const int col = n * 16 + l16;
        gt[w * 32 + m * 16 + cr + e][col] =
            acc[m][n][e] + (col < NOUT ? b3[col] : 0.f);
      }
  __syncthreads();
  if (tid < 128) {
    float mx = -INFINITY;
#pragma unroll
    for (int j = 0; j < NOUT; ++j) mx = fmaxf(mx, gt[tid][j]);
    float s = 0.f;
#pragma unroll
    for (int j = 0; j < NOUT; ++j) s += expf(gt[tid][j] - mx);
    lseb[tid] = logf(s) + mx;
  }
  __syncthreads();
  for (int idx = tid; idx < 128 * NOUT; idx += 256) {
    const int r = idx / NOUT, j = idx - r * NOUT;
    out[(size_t)(r0 + r) * NOUT + j] = gt[r][j] - lseb[r];
  }
}

// ---------------------------------------------------------------------------
// Prep kernels
// ---------------------------------------------------------------------------
__global__ void prep_w(const float* __restrict__ ih, const float* __restrict__ hh,
                       unsigned short* __restrict__ dst, int HU, int KI, int KH) {
  const int K = KI + KH;
  const long tot = (long)HU * 4 * K;
  for (long idx = (long)blockIdx.x * blockDim.x + threadIdx.x; idx < tot;
       idx += (long)gridDim.x * blockDim.x) {
    const int row = (int)(idx / K), k = (int)(idx % K);
    const int u = row >> 2, g = row & 3;
    const float v = (k < KI) ? ih[(size_t)(g * HU + u) * KI + k]
                             : hh[(size_t)(g * HU + u) * KH + (k - KI)];
    dst[idx] = f2bu(v);
  }
}

__global__ void prep_bias(const float* bih, const float* bhh, float* dst, int HU) {
  const int idx = blockIdx.x * blockDim.x + threadIdx.x;
  if (idx < 4 * HU) {
    const int u = idx >> 2, g = idx & 3;
    dst[idx] = bih[g * HU + u] + bhh[g * HU + u];
  }
}

__global__ void conv_bf(const float* __restrict__ src, unsigned short* __restrict__ dst,
                        long n) {
  for (long i = (long)blockIdx.x * blockDim.x + threadIdx.x; i < n;
       i += (long)gridDim.x * blockDim.x)
    dst[i] = f2bu(src[i]);
}

__global__ void prep_w3(const float* __restrict__ W3, unsigned short* __restrict__ dst) {
  const int i = blockIdx.x * blockDim.x + threadIdx.x;   // 64*256
  if (i < 64 * 256) {
    const int r = i >> 8;
    dst[i] = (r < NOUT) ? f2bu(W3[i]) : 0;
  }
}

__global__ void lengths_k(const int* x, int* len) {
  const int n = blockIdx.x * blockDim.x + threadIdx.x;
  if (n < NW) {
    int c = 0;
#pragma unroll
    for (int l = 0; l < LC; ++l) c += (x[(size_t)n * LC + l] != 0) ? 1 : 0;
    len[n] = c;
  }
}

__global__ void zero_cnts(int* cnts) {
  if (threadIdx.x < 128) cnts[threadIdx.x] = 0;
}

__global__ void sentinel_k(float* out, int n) {
  const int i = blockIdx.x * blockDim.x + threadIdx.x;
  if (i < n) out[i] = 1000.0f;
}

// ---------------------------------------------------------------------------
extern "C" void kernel_launch(void* const* d_in, const int* in_sizes, int n_in,
                              void* d_out, int out_size, void* d_ws, size_t ws_size,
                              hipStream_t stream) {
  const int*   x     = (const int*)d_in[0];
  const float* emb   = (const float*)d_in[1];
  const float* cW_ih = (const float*)d_in[2];
  const float* cW_hh = (const float*)d_in[3];
  const float* cb_ih = (const float*)d_in[4];
  const float* cb_hh = (const float*)d_in[5];
  const float* fW_ih = (const float*)d_in[6];
  const float* fW_hh = (const float*)d_in[7];
  const float* fb_ih = (const float*)d_in[8];
  const float* fb_hh = (const float*)d_in[9];
  const float* bW_ih = (const float*)d_in[10];
  const float* bW_hh = (const float*)d_in[11];
  const float* bb_ih = (const float*)d_in[12];
  const float* bb_hh = (const float*)d_in[13];
  const float* W1 = (const float*)d_in[14];
  const float* b1 = (const float*)d_in[15];
  const float* W2 = (const float*)d_in[16];
  const float* b2 = (const float*)d_in[17];
  const float* W3 = (const float*)d_in[18];
  const float* b3 = (const float*)d_in[19];
  float* out = (float*)d_out;
  (void)in_sizes; (void)n_in;

  char* ws = (char*)d_ws;
  size_t off = 0;
  auto alloc = [&](size_t bytes) -> char* {
    char* p = ws + off;
    off += (bytes + 255) & ~(size_t)255;
    return p;
  };
  int*            len_ = (int*)alloc((size_t)NW * 4);
  int*            cnts = (int*)alloc(128 * 4);
  unsigned short* embb = (unsigned short*)alloc((size_t)100 * EDIM * 2);
  unsigned short* Wc_i = (unsigned short*)alloc((size_t)1024 * 320 * 2);
  unsigned short* Wf_i = (unsigned short*)alloc((size_t)2048 * 768 * 2);
  unsigned short* Wb_i = (unsigned short*)alloc((size_t)2048 * 768 * 2);
  unsigned short* W1b  = (unsigned short*)alloc((size_t)256 * 1024 * 2);
  unsigned short* W2b  = (unsigned short*)alloc((size_t)256 * 256 * 2);
  unsigned short* W3p  = (unsigned short*)alloc((size_t)64 * 256 * 2);
  float*          bc_i = (float*)alloc(1024 * 4);
  float*          bf_i = (float*)alloc(2048 * 4);
  float*          bb_i = (float*)alloc(2048 * 4);
  unsigned short* last = (unsigned short*)alloc((size_t)NW * HC * 2);     // 8MB
  unsigned short* hb   = (unsigned short*)alloc((size_t)4 * SEQ * HW * 2);// 512KB
  unsigned short* hs   = (unsigned short*)alloc((size_t)NW * 1024 * 2);   // 32MB
  unsigned short* h1   = (unsigned short*)alloc((size_t)NW * HC * 2);     // 8MB
  unsigned short* h2   = (unsigned short*)alloc((size_t)NW * HC * 2);     // 8MB

  if (off > ws_size) {
    sentinel_k<<<(out_size + 255) / 256, 256, 0, stream>>>(out, out_size);
    return;
  }

  auto cdiv = [](long a, long b) { return (int)((a + b - 1) / b); };

  // ---- prep ----
  prep_w<<<1280, 256, 0, stream>>>(cW_ih, cW_hh, Wc_i, HC, EDIM, HC);
  prep_w<<<3072, 256, 0, stream>>>(fW_ih, fW_hh, Wf_i, HW, HC, HW);
  prep_w<<<3072, 256, 0, stream>>>(bW_ih, bW_hh, Wb_i, HW, HC, HW);
  prep_bias<<<cdiv(1024, 256), 256, 0, stream>>>(cb_ih, cb_hh, bc_i, HC);
  prep_bias<<<cdiv(2048, 256), 256, 0, stream>>>(fb_ih, fb_hh, bf_i, HW);
  prep_bias<<<cdiv(2048, 256), 256, 0, stream>>>(bb_ih, bb_hh, bb_i, HW);
  conv_bf<<<25, 256, 0, stream>>>(emb, embb, 100L * EDIM);
  conv_bf<<<1024, 256, 0, stream>>>(W1, W1b, 256L * 1024);
  conv_bf<<<256, 256, 0, stream>>>(W2, W2b, 256L * 256);
  prep_w3<<<64, 256, 0, stream>>>(W3, W3p);
  lengths_k<<<cdiv(NW, 256), 256, 0, stream>>>(x, len_);
  zero_cnts<<<1, 128, 0, stream>>>(cnts);

  // ---- persistent char LSTM (1 launch) ----
  char_lstm<<<NW / 32, 256, 0, stream>>>(x, embb, Wc_i, bc_i, last, len_);

  // ---- persistent word BiLSTM (1 launch, spin-barrier per step) ----
  word_lstm<<<NWB, 256, 0, stream>>>(last, Wf_i, Wb_i, bf_i, bb_i, hb, hs, cnts);

  // ---- MLP + fused logits/log_softmax ----
  mlp_gemm<<<dim3(4, 128), 256, 0, stream>>>(hs, 1024, W1b, 1024, b1, h1, 256, 32, 1);
  mlp_gemm<<<dim3(4, 128), 256, 0, stream>>>(h1, 256, W2b, 256, b2, h2, 256, 8, 1);
  logits_fused<<<NW / 128, 256, 0, stream>>>(h2, W3p, b3, out);
}

// Round 6
// 4581.691 us; speedup vs baseline: 1.1112x; 1.1112x over previous
//
#include <hip/hip_runtime.h>
#include <hip/hip_bf16.h>
#include <math.h>

typedef __hip_bfloat16 bf16;
typedef __attribute__((ext_vector_type(8))) short bf16x8;   // 8 bf16 = 4 VGPR
typedef __attribute__((ext_vector_type(4))) float f32x4;

#define NW   16384
#define LC   20
#define EDIM 64
#define HC   256
#define HW   512
#define SEQ  128
#define NOUT 50
#define NWB  64      // word-kernel block count (must all be co-resident)

__device__ __forceinline__ float sigf(float x) { return 1.0f / (1.0f + expf(-x)); }
__device__ __forceinline__ float bu2f(unsigned short b) {
  union { float f; unsigned u; } z; z.u = ((unsigned)b) << 16; return z.f;
}
__device__ __forceinline__ unsigned short f2bu(float f) {
  bf16 h = __float2bfloat16(f);
  return *reinterpret_cast<unsigned short*>(&h);
}
__device__ __forceinline__ bf16x8 ld8(const unsigned short* p) {
  return *reinterpret_cast<const bf16x8*>(p);
}
// Coherent (cross-XCD) 16B load/store via agent-scope relaxed atomics:
// lowers to global_load/store with sc0 sc1 -> bypasses non-coherent L1/L2.
__device__ __forceinline__ bf16x8 ld8c(const unsigned short* p) {
  union { bf16x8 v; unsigned long long q[2]; } z;
  unsigned long long* a = (unsigned long long*)p;
  z.q[0] = __hip_atomic_load(a + 0, __ATOMIC_RELAXED, __HIP_MEMORY_SCOPE_AGENT);
  z.q[1] = __hip_atomic_load(a + 1, __ATOMIC_RELAXED, __HIP_MEMORY_SCOPE_AGENT);
  return z.v;
}
__device__ __forceinline__ void st8c(unsigned short* p, unsigned long long q0,
                                     unsigned long long q1) {
  unsigned long long* a = (unsigned long long*)p;
  __hip_atomic_store(a + 0, q0, __ATOMIC_RELAXED, __HIP_MEMORY_SCOPE_AGENT);
  __hip_atomic_store(a + 1, q1, __ATOMIC_RELAXED, __HIP_MEMORY_SCOPE_AGENT);
}
#define MFMA(a, b, c) __builtin_amdgcn_mfma_f32_16x16x32_bf16(a, b, c, 0, 0, 0)

// ---------------------------------------------------------------------------
// Persistent char LSTM: one launch, 512 blocks x 32 words. h in LDS
// (double-buffered), c in registers. Weights (gate-interleaved bf16) stream
// from L2. One __syncthreads per step. last written once per word.
// ---------------------------------------------------------------------------
__global__ __launch_bounds__(256) void char_lstm(
    const int* __restrict__ x, const unsigned short* __restrict__ embb,
    const unsigned short* __restrict__ Wc, const float* __restrict__ bc,
    unsigned short* __restrict__ last, const int* __restrict__ len) {
  __shared__ unsigned short Hs[2][32][264];   // 33.8 KB
  __shared__ float gt[4][32][68];             // 34.8 KB
  const int tid = threadIdx.x;
  const int w = tid >> 6, l = tid & 63;
  const int l16 = l & 15, lk8 = (l >> 4) * 8;
  const int hi = l >> 5;              // 0/1
  const int wl = l & 31;              // owned word (update phase)
  const int w0 = blockIdx.x * 32;
  const int mylen = len[w0 + wl];
  float cst[4][8];
#pragma unroll
  for (int c = 0; c < 4; ++c)
#pragma unroll
    for (int i = 0; i < 8; ++i) cst[c][i] = 0.f;

  for (int t = 0; t < LC; ++t) {
    const int cur = t & 1, nxt = cur ^ 1;
    const int xi0 = x[(w0 + l16) * LC + t];
    const int xi1 = x[(w0 + 16 + l16) * LC + t];
#pragma unroll
    for (int c = 0; c < 4; ++c) {
      const int cc0 = w * 256 + c * 64;
      f32x4 acc[2][4] = {};
#pragma unroll
      for (int kk = 0; kk < 2; ++kk) {          // K 0..63: embedding
        const int k = kk * 32 + lk8;
        bf16x8 a0 = ld8(embb + (size_t)xi0 * EDIM + k);
        bf16x8 a1 = ld8(embb + (size_t)xi1 * EDIM + k);
        const unsigned short* wp = Wc + (size_t)(cc0 + l16) * 320 + k;
#pragma unroll
        for (int n = 0; n < 4; ++n) {
          bf16x8 bv = ld8(wp + n * 16 * 320);
          acc[0][n] = MFMA(a0, bv, acc[0][n]);
          acc[1][n] = MFMA(a1, bv, acc[1][n]);
        }
      }
      if (t > 0) {
#pragma unroll
        for (int kk = 2; kk < 10; ++kk) {       // K 64..319: h(t-1) from LDS
          const int k = kk * 32 + lk8;
          bf16x8 a0 = ld8(&Hs[cur][l16][k - 64]);
          bf16x8 a1 = ld8(&Hs[cur][16 + l16][k - 64]);
          const unsigned short* wp = Wc + (size_t)(cc0 + l16) * 320 + k;
#pragma unroll
          for (int n = 0; n < 4; ++n) {
            bf16x8 bv = ld8(wp + n * 16 * 320);
            acc[0][n] = MFMA(a0, bv, acc[0][n]);
            acc[1][n] = MFMA(a1, bv, acc[1][n]);
          }
        }
      }
      const int cr = (l >> 4) * 4;
#pragma unroll
      for (int m = 0; m < 2; ++m)
#pragma unroll
        for (int n = 0; n < 4; ++n)
#pragma unroll
          for (int e = 0; e < 4; ++e)
            gt[w][m * 16 + cr + e][n * 16 + l16] = acc[m][n][e];
      // same-wave LDS RAW: compiler inserts lgkmcnt waits
#pragma unroll
      for (int i = 0; i < 8; ++i) {
        const int ul = 2 * i + hi;              // unit-local 0..15
        const int col = 4 * ul;
        float gi = gt[w][wl][col + 0] + bc[cc0 + col + 0];
        float gf = gt[w][wl][col + 1] + bc[cc0 + col + 1];
        float gg = gt[w][wl][col + 2] + bc[cc0 + col + 2];
        float go = gt[w][wl][col + 3] + bc[cc0 + col + 3];
        float cc = sigf(gf) * cst[c][i] + sigf(gi) * tanhf(gg);
        cst[c][i] = cc;
        float h = sigf(go) * tanhf(cc);
        const int unit = (cc0 >> 2) + ul;
        Hs[nxt][wl][unit] = f2bu(h);
        if (t == mylen - 1)
          last[(size_t)(w0 + wl) * HC + unit] = f2bu(h);
        else if (mylen == 0 && t == 0)
          last[(size_t)(w0 + wl) * HC + unit] = 0;   // bf16 +0
      }
    }
    __syncthreads();   // Hs[nxt] complete before next step's reads
  }
}

// ---------------------------------------------------------------------------
// Persistent word BiLSTM: one launch, 64 blocks (dir = bx>>5, 64 gate-cols
// each). M=128 batches per block. h exchanged via coherent (sc0 sc1) 16B
// atomics -> no threadfence, weights stay warm in per-XCD L2. Fence-free
// spin barrier per step, per-direction (count to 32).
// ---------------------------------------------------------------------------
__global__ __launch_bounds__(256) void word_lstm(
    const unsigned short* __restrict__ last,
    const unsigned short* __restrict__ Wf, const unsigned short* __restrict__ Wb,
    const float* __restrict__ bfi, const float* __restrict__ bbi,
    unsigned short* __restrict__ hb,    // [2 buf][2 dir][128][512]
    unsigned short* __restrict__ hs,    // [16384][1024]
    int* __restrict__ cnts) {           // [2 dir][128]
  __shared__ float gt[128][69];         // 35.3 KB
  const int tid = threadIdx.x;
  const int w = tid >> 6, l = tid & 63;
  const int l16 = l & 15, lk8 = (l >> 4) * 8;
  const int dir = blockIdx.x >> 5;
  const int nb = blockIdx.x & 31;
  const int c0 = nb * 64;               // gate-col base (of 2048)
  const int u0 = nb * 16;               // unit base (of 512)
  const unsigned short* W = dir ? Wb : Wf;
  const float* bias = dir ? bbi : bfi;
  const int ub = tid & 127;             // owned batch
  const int uhi = tid >> 7;             // 0/1 -> units u0+8*uhi .. +8
  int* mycnt = cnts + dir * SEQ;
  float cst[8];
#pragma unroll
  for (int i = 0; i < 8; ++i) cst[i] = 0.f;

  for (int t = 0; t < SEQ; ++t) {
    const int cur = t & 1;
    const int pos = dir ? (SEQ - 1 - t) : t;
    const unsigned short* hprev = hb + (size_t)(((cur ^ 1) << 1) + dir) * SEQ * HW;
    const int bt0 = w * 32 + l16, bt1 = bt0 + 16;
    f32x4 acc[2][4] = {};
#pragma unroll
    for (int kk = 0; kk < 8; ++kk) {            // K 0..255: word_seq (cached)
      const int k = kk * 32 + lk8;
      bf16x8 a0 = ld8(last + ((size_t)bt0 * SEQ + pos) * HC + k);
      bf16x8 a1 = ld8(last + ((size_t)bt1 * SEQ + pos) * HC + k);
      const unsigned short* wp = W + (size_t)(c0 + l16) * 768 + k;
#pragma unroll
      for (int n = 0; n < 4; ++n) {
        bf16x8 bv = ld8(wp + n * 16 * 768);
        acc[0][n] = MFMA(a0, bv, acc[0][n]);
        acc[1][n] = MFMA(a1, bv, acc[1][n]);
      }
    }
    if (t > 0) {
#pragma unroll
      for (int kk = 8; kk < 24; ++kk) {         // K 256..767: h(t-1), coherent
        const int k = kk * 32 + lk8;
        bf16x8 a0 = ld8c(hprev + (size_t)bt0 * HW + (k - HC));
        bf16x8 a1 = ld8c(hprev + (size_t)bt1 * HW + (k - HC));
        const unsigned short* wp = W + (size_t)(c0 + l16) * 768 + k;
#pragma unroll
        for (int n = 0; n < 4; ++n) {
          bf16x8 bv = ld8(wp + n * 16 * 768);
          acc[0][n] = MFMA(a0, bv, acc[0][n]);
          acc[1][n] = MFMA(a1, bv, acc[1][n]);
        }
      }
    }
    const int cr = (l >> 4) * 4;
#pragma unroll
    for (int m = 0; m < 2; ++m)
#pragma unroll
      for (int n = 0; n < 4; ++n)
#pragma unroll
        for (int e = 0; e < 4; ++e)
          gt[w * 32 + m * 16 + cr + e][n * 16 + l16] = acc[m][n][e];
    __syncthreads();
    union { unsigned short s[8]; unsigned long long q[2]; bf16x8 v; } hv;
#pragma unroll
    for (int i = 0; i < 8; ++i) {
      const int ul = uhi * 8 + i;               // unit-local 0..15
      const int col = 4 * ul;
      float gi = gt[ub][col + 0] + bias[c0 + col + 0];
      float gf = gt[ub][col + 1] + bias[c0 + col + 1];
      float gg = gt[ub][col + 2] + bias[c0 + col + 2];
      float go = gt[ub][col + 3] + bias[c0 + col + 3];
      float cc = sigf(gf) * cst[i] + sigf(gi) * tanhf(gg);
      cst[i] = cc;
      hv.s[i] = f2bu(sigf(go) * tanhf(cc));
    }
    unsigned short* hcur = hb + (size_t)((cur << 1) + dir) * SEQ * HW
                         + (size_t)ub * HW + u0 + uhi * 8;
    st8c(hcur, hv.q[0], hv.q[1]);               // coherent 16B store
    *reinterpret_cast<bf16x8*>(
        hs + ((size_t)ub * SEQ + pos) * 1024 + dir * HW + u0 + uhi * 8) = hv.v;
    if (t < SEQ - 1) {
      // fence-free barrier: sc1 stores are at the coherence point once
      // vmcnt drains; no L2 invalidate needed (hprev reads are sc1 too).
      asm volatile("s_waitcnt vmcnt(0)" ::: "memory");
      __syncthreads();
      if (tid == 0) {
        __hip_atomic_fetch_add(mycnt + t, 1, __ATOMIC_RELAXED,
                               __HIP_MEMORY_SCOPE_AGENT);
        while (__hip_atomic_load(mycnt + t, __ATOMIC_RELAXED,
                                 __HIP_MEMORY_SCOPE_AGENT) < NWB / 2)
          __builtin_amdgcn_s_sleep(1);
      }
      __syncthreads();
    }
  }
}

// ---------------------------------------------------------------------------
// MLP GEMM: out = relu(A @ W^T + bias), bf16 in/out, 128x64 per block.
// ---------------------------------------------------------------------------
__global__ __launch_bounds__(256) void mlp_gemm(
    const unsigned short* __restrict__ A, int lda,
    const unsigned short* __restrict__ W, int ldw,
    const float* __restrict__ bias, unsigned short* __restrict__ out,
    int ldo, int nk, int relu) {
  const int tid = threadIdx.x;
  const int w = tid >> 6, l = tid & 63;
  const int l16 = l & 15, lk8 = (l >> 4) * 8;
  const int row0 = blockIdx.y * 128 + w * 32;
  const int col0 = blockIdx.x * 64;
  f32x4 acc[2][4] = {};
  for (int kk = 0; kk < nk; ++kk) {
    const int k = kk * 32 + lk8;
    bf16x8 a0 = ld8(A + (size_t)(row0 + l16) * lda + k);
    bf16x8 a1 = ld8(A + (size_t)(row0 + 16 + l16) * lda + k);
    const unsigned short* wp = W + (size_t)(col0 + l16) * ldw + k;
    bf16x8 bb[4];
#pragma unroll
    for (int n = 0; n < 4; ++n) bb[n] = ld8(wp + n * 16 * ldw);
#pragma unroll
    for (int n = 0; n < 4; ++n) {
      acc[0][n] = MFMA(a0, bb[n], acc[0][n]);
      acc[1][n] = MFMA(a1, bb[n], acc[1][n]);
    }
  }
  const int cr = (l >> 4) * 4;
#pragma unroll
  for (int m = 0; m < 2; ++m)
#pragma unroll
    for (int n = 0; n < 4; ++n)
#pragma unroll
      for (int e = 0; e < 4; ++e) {
        const int r = row0 + m * 16 + cr + e;
        const int c = col0 + n * 16 + l16;
        float v = acc[m][n][e] + bias[c];
        if (relu) v = fmaxf(v, 0.f);
        out[(size_t)r * ldo + c] = f2bu(v);
      }
}

// ---------------------------------------------------------------------------
// Logits (MFMA, N=64 padded) + log_softmax over 50, fused. 128 rows/block.
// ---------------------------------------------------------------------------
__global__ __launch_bounds__(256) void logits_fused(
    const unsigned short* __restrict__ h2, const unsigned short* __restrict__ W3p,
    const float* __restrict__ b3, float* __restrict__ out) {
  __shared__ float gt[128][68];
  __shared__ float lseb[128];
  const int tid = threadIdx.x;
  const int w = tid >> 6, l = tid & 63;
  const int l16 = l & 15, lk8 = (l >> 4) * 8;
  const int r0 = blockIdx.x * 128;
  const int rr0 = w * 32 + l16, rr1 = rr0 + 16;
  f32x4 acc[2][4] = {};
#pragma unroll
  for (int kk = 0; kk < 8; ++kk) {
    const int k = kk * 32 + lk8;
    bf16x8 a0 = ld8(h2 + (size_t)(r0 + rr0) * 256 + k);
    bf16x8 a1 = ld8(h2 + (size_t)(r0 + rr1) * 256 + k);
#pragma unroll
    for (int n = 0; n < 4; ++n) {
      bf16x8 bv = ld8(W3p + (size_t)(n * 16 + l16) * 256 + k);
      acc[0][n] = MFMA(a0, bv, acc[0][n]);
      acc[1][n] = MFMA(a1, bv, acc[1][n]);
    }
  }
  const int cr = (l >> 4) * 4;
#pragma unroll
  for (int m = 0; m < 2; ++m)
#pragma unroll
    for (int n = 0; n < 4; ++n)
#pragma unroll
      for (int e = 0; e < 4; ++e) {
        const int col = n * 16 + l16;
        gt[w * 32 + m * 16 + cr + e][col] =
            acc[m][n][e] + (col < NOUT ? b3[col] : 0.f);
      }
  __syncthreads();
  if (tid < 128) {
    float mx = -INFINITY;
#pragma unroll
    for (int j = 0; j < NOUT; ++j) mx = fmaxf(mx, gt[tid][j]);
    float s = 0.f;
#pragma unroll
    for (int j = 0; j < NOUT; ++j) s += expf(gt[tid][j] - mx);
    lseb[tid] = logf(s) + mx;
  }
  __syncthreads();
  for (int idx = tid; idx < 128 * NOUT; idx += 256) {
    const int r = idx / NOUT, j = idx - r * NOUT;
    out[(size_t)(r0 + r) * NOUT + j] = gt[r][j] - lseb[r];
  }
}

// ---------------------------------------------------------------------------
// Prep kernels
// ---------------------------------------------------------------------------
__global__ void prep_w(const float* __restrict__ ih, const float* __restrict__ hh,
                       unsigned short* __restrict__ dst, int HU, int KI, int KH) {
  const int K = KI + KH;
  const long tot = (long)HU * 4 * K;
  for (long idx = (long)blockIdx.x * blockDim.x + threadIdx.x; idx < tot;
       idx += (long)gridDim.x * blockDim.x) {
    const int row = (int)(idx / K), k = (int)(idx % K);
    const int u = row >> 2, g = row & 3;
    const float v = (k < KI) ? ih[(size_t)(g * HU + u) * KI + k]
                             : hh[(size_t)(g * HU + u) * KH + (k - KI)];
    dst[idx] = f2bu(v);
  }
}

__global__ void prep_bias(const float* bih, const float* bhh, float* dst, int HU) {
  const int idx = blockIdx.x * blockDim.x + threadIdx.x;
  if (idx < 4 * HU) {
    const int u = idx >> 2, g = idx & 3;
    dst[idx] = bih[g * HU + u] + bhh[g * HU + u];
  }
}

__global__ void conv_bf(const float* __restrict__ src, unsigned short* __restrict__ dst,
                        long n) {
  for (long i = (long)blockIdx.x * blockDim.x + threadIdx.x; i < n;
       i += (long)gridDim.x * blockDim.x)
    dst[i] = f2bu(src[i]);
}

__global__ void prep_w3(const float* __restrict__ W3, unsigned short* __restrict__ dst) {
  const int i = blockIdx.x * blockDim.x + threadIdx.x;   // 64*256
  if (i < 64 * 256) {
    const int r = i >> 8;
    dst[i] = (r < NOUT) ? f2bu(W3[i]) : 0;
  }
}

__global__ void lengths_k(const int* x, int* len) {
  const int n = blockIdx.x * blockDim.x + threadIdx.x;
  if (n < NW) {
    int c = 0;
#pragma unroll
    for (int l = 0; l < LC; ++l) c += (x[(size_t)n * LC + l] != 0) ? 1 : 0;
    len[n] = c;
  }
}

__global__ void zero_cnts(int* cnts) {
  if (threadIdx.x < 256) cnts[threadIdx.x] = 0;
}

__global__ void sentinel_k(float* out, int n) {
  const int i = blockIdx.x * blockDim.x + threadIdx.x;
  if (i < n) out[i] = 1000.0f;
}

// ---------------------------------------------------------------------------
extern "C" void kernel_launch(void* const* d_in, const int* in_sizes, int n_in,
                              void* d_out, int out_size, void* d_ws, size_t ws_size,
                              hipStream_t stream) {
  const int*   x     = (const int*)d_in[0];
  const float* emb   = (const float*)d_in[1];
  const float* cW_ih = (const float*)d_in[2];
  const float* cW_hh = (const float*)d_in[3];
  const float* cb_ih = (const float*)d_in[4];
  const float* cb_hh = (const float*)d_in[5];
  const float* fW_ih = (const float*)d_in[6];
  const float* fW_hh = (const float*)d_in[7];
  const float* fb_ih = (const float*)d_in[8];
  const float* fb_hh = (const float*)d_in[9];
  const float* bW_ih = (const float*)d_in[10];
  const float* bW_hh = (const float*)d_in[11];
  const float* bb_ih = (const float*)d_in[12];
  const float* bb_hh = (const float*)d_in[13];
  const float* W1 = (const float*)d_in[14];
  const float* b1 = (const float*)d_in[15];
  const float* W2 = (const float*)d_in[16];
  const float* b2 = (const float*)d_in[17];
  const float* W3 = (const float*)d_in[18];
  const float* b3 = (const float*)d_in[19];
  float* out = (float*)d_out;
  (void)in_sizes; (void)n_in;

  char* ws = (char*)d_ws;
  size_t off = 0;
  auto alloc = [&](size_t bytes) -> char* {
    char* p = ws + off;
    off += (bytes + 255) & ~(size_t)255;
    return p;
  };
  int*            len_ = (int*)alloc((size_t)NW * 4);
  int*            cnts = (int*)alloc(2 * SEQ * 4);
  unsigned short* embb = (unsigned short*)alloc((size_t)100 * EDIM * 2);
  unsigned short* Wc_i = (unsigned short*)alloc((size_t)1024 * 320 * 2);
  unsigned short* Wf_i = (unsigned short*)alloc((size_t)2048 * 768 * 2);
  unsigned short* Wb_i = (unsigned short*)alloc((size_t)2048 * 768 * 2);
  unsigned short* W1b  = (unsigned short*)alloc((size_t)256 * 1024 * 2);
  unsigned short* W2b  = (unsigned short*)alloc((size_t)256 * 256 * 2);
  unsigned short* W3p  = (unsigned short*)alloc((size_t)64 * 256 * 2);
  float*          bc_i = (float*)alloc(1024 * 4);
  float*          bf_i = (float*)alloc(2048 * 4);
  float*          bb_i = (float*)alloc(2048 * 4);
  unsigned short* last = (unsigned short*)alloc((size_t)NW * HC * 2);     // 8MB
  unsigned short* hb   = (unsigned short*)alloc((size_t)4 * SEQ * HW * 2);// 512KB
  unsigned short* hs   = (unsigned short*)alloc((size_t)NW * 1024 * 2);   // 32MB
  unsigned short* h1   = (unsigned short*)alloc((size_t)NW * HC * 2);     // 8MB
  unsigned short* h2   = (unsigned short*)alloc((size_t)NW * HC * 2);     // 8MB

  if (off > ws_size) {
    sentinel_k<<<(out_size + 255) / 256, 256, 0, stream>>>(out, out_size);
    return;
  }

  auto cdiv = [](long a, long b) { return (int)((a + b - 1) / b); };

  // ---- prep ----
  prep_w<<<1280, 256, 0, stream>>>(cW_ih, cW_hh, Wc_i, HC, EDIM, HC);
  prep_w<<<3072, 256, 0, stream>>>(fW_ih, fW_hh, Wf_i, HW, HC, HW);
  prep_w<<<3072, 256, 0, stream>>>(bW_ih, bW_hh, Wb_i, HW, HC, HW);
  prep_bias<<<cdiv(1024, 256), 256, 0, stream>>>(cb_ih, cb_hh, bc_i, HC);
  prep_bias<<<cdiv(2048, 256), 256, 0, stream>>>(fb_ih, fb_hh, bf_i, HW);
  prep_bias<<<cdiv(2048, 256), 256, 0, stream>>>(bb_ih, bb_hh, bb_i, HW);
  conv_bf<<<25, 256, 0, stream>>>(emb, embb, 100L * EDIM);
  conv_bf<<<1024, 256, 0, stream>>>(W1, W1b, 256L * 1024);
  conv_bf<<<256, 256, 0, stream>>>(W2, W2b, 256L * 256);
  prep_w3<<<64, 256, 0, stream>>>(W3, W3p);
  lengths_k<<<cdiv(NW, 256), 256, 0, stream>>>(x, len_);
  zero_cnts<<<1, 256, 0, stream>>>(cnts);

  // ---- persistent char LSTM (1 launch) ----
  char_lstm<<<NW / 32, 256, 0, stream>>>(x, embb, Wc_i, bc_i, last, len_);

  // ---- persistent word BiLSTM (1 launch, fence-free spin barriers) ----
  word_lstm<<<NWB, 256, 0, stream>>>(last, Wf_i, Wb_i, bf_i, bb_i, hb, hs, cnts);

  // ---- MLP + fused logits/log_softmax ----
  mlp_gemm<<<dim3(4, 128), 256, 0, stream>>>(hs, 1024, W1b, 1024, b1, h1, 256, 32, 1);
  mlp_gemm<<<dim3(4, 128), 256, 0, stream>>>(h1, 256, W2b, 256, b2, h2, 256, 8, 1);
  logits_fused<<<NW / 128, 256, 0, stream>>>(h2, W3p, b3, out);
}